// Round 5
// baseline (345.345 us; speedup 1.0000x reference)
//
#include <hip/hip_runtime.h>
#include <hip/hip_bf16.h>

#define B_ 8
#define N_ 2048
#define D_ 64

typedef __attribute__((ext_vector_type(8))) short bf16x8;
typedef __attribute__((ext_vector_type(4))) float f32x4;

__device__ inline unsigned short f32_bf16_rne(float f) {
    unsigned u = __float_as_uint(f);
    u += 0x7fffu + ((u >> 16) & 1u);
    return (unsigned short)(u >> 16);
}

// Kernel A: h = feats @ W^T (fp32), a_src/a_dst reductions, store hT[b][d][j] as bf16.
__global__ __launch_bounds__(256) void prep_kernel(
    const float* __restrict__ feats, const float* __restrict__ W,
    const float* __restrict__ attn_src, const float* __restrict__ attn_dst,
    unsigned short* __restrict__ hT, float* __restrict__ a_src,
    float* __restrict__ a_dst) {
    __shared__ float w_lds[64 * 65];
    __shared__ float f_lds[32 * 64];
    __shared__ unsigned short hT_lds[64 * 40];

    const int t = threadIdx.x;
    const int b = blockIdx.x >> 6;
    const int rowbase = (blockIdx.x & 63) * 32;

#pragma unroll
    for (int k = 0; k < 4; k++) {
        int lin = (k * 256 + t) * 4;
        float4 v = *(const float4*)(W + lin);
        int o = lin >> 6, d = lin & 63;
        float* p = &w_lds[o * 65 + d];
        p[0] = v.x; p[1] = v.y; p[2] = v.z; p[3] = v.w;
    }
#pragma unroll
    for (int k = 0; k < 2; k++) {
        int lin = (k * 256 + t) * 4;
        float4 v = *(const float4*)(feats + (size_t)(b * N_ + rowbase) * D_ + lin);
        float* p = &f_lds[lin];
        p[0] = v.x; p[1] = v.y; p[2] = v.z; p[3] = v.w;
    }
    __syncthreads();

    const int w = t >> 6;
    const int o = t & 63;
    float acc[8] = {0.f, 0.f, 0.f, 0.f, 0.f, 0.f, 0.f, 0.f};
#pragma unroll 8
    for (int d = 0; d < 64; d++) {
        float wv = w_lds[o * 65 + d];
#pragma unroll
        for (int rr = 0; rr < 8; rr++)
            acc[rr] = fmaf(f_lds[(w * 8 + rr) * 64 + d], wv, acc[rr]);
    }
    float as_ = attn_src[o], ad_ = attn_dst[o];
#pragma unroll
    for (int rr = 0; rr < 8; rr++) {
        int row = rowbase + w * 8 + rr;
        float s1 = acc[rr] * as_;
        float s2 = acc[rr] * ad_;
#pragma unroll
        for (int off = 32; off; off >>= 1) {
            s1 += __shfl_xor(s1, off);
            s2 += __shfl_xor(s2, off);
        }
        if (o == 0) {
            a_src[b * N_ + row] = s1;
            a_dst[b * N_ + row] = s2;
        }
        hT_lds[o * 40 + w * 8 + rr] = f32_bf16_rne(acc[rr]);
    }
    __syncthreads();
    const int d = t >> 2, seg = t & 3;
    uint4 vv = *(const uint4*)(&hT_lds[d * 40 + seg * 8]);
    *(uint4*)(hT + ((size_t)(b * 64 + d) * N_ + rowbase + seg * 8)) = vv;
}

// Kernel B: masked dual-softmax partial attention via bf16 MFMA.
// Grid: x = 256 row-tiles (b*32+rt), y = S j-slices. 256 threads / 4 waves,
// wave = 16-row group over this block's j-slice. VGPR-proven config (round 2:
// 116 VGPRs, zero spill). Writes fp32 partial acc (32 KB) + partial Z to ws.
__global__ __launch_bounds__(256) void attn_kernel(
    const int* __restrict__ mask_adj, const int* __restrict__ mask_job,
    const int* __restrict__ batch_idxes,
    const unsigned short* __restrict__ hT, const float* __restrict__ a_src,
    const float* __restrict__ a_dst, float* __restrict__ pacc,
    float* __restrict__ zpart) {
    __shared__ unsigned short hstage[64 * 128];  // XOR-swizzled 16B chunks

    const int t = threadIdx.x;
    const int tile = blockIdx.x;
    const int b2 = tile >> 5;
    const int ib2 = (tile & 31) * 64;
    const int S = gridDim.y;
    const int jcount = (N_ / 128) / S;           // 128-j tiles in this slice
    const int j0base = blockIdx.y * jcount * 128;

    const int wid = t >> 6, lane = t & 63;
    const int m = lane & 15, q = lane >> 4;
    const int irow0 = ib2 + wid * 16;
    const int i_a = irow0 + m;

    int bi = batch_idxes[b2];                    // int32 on device; clamp = no-fault
    bi = (bi < 0) ? 0 : ((bi >= B_) ? (B_ - 1) : bi);
    const int* mA = mask_adj + (size_t)bi * N_ * N_ + (size_t)i_a * N_;
    const int* mJ = mask_job + (size_t)bi * N_ * N_ + (size_t)i_a * N_;
    const float asrc = a_src[b2 * N_ + i_a];
    const float* adst = a_dst + b2 * N_;

    f32x4 accA[4], accJ[4];
#pragma unroll
    for (int dd = 0; dd < 4; dd++) {
        accA[dd] = (f32x4){0.f, 0.f, 0.f, 0.f};
        accJ[dd] = (f32x4){0.f, 0.f, 0.f, 0.f};
    }
    float zA = 0.f, zJ = 0.f;

    const int sd = t >> 2, sseg = t & 3;         // staging: row d, 4-chunk segment
    const unsigned short* hrow = hT + (size_t)(b2 * 64 + sd) * N_;

    for (int jt = 0; jt < jcount; jt++) {
        const int j0 = j0base + jt * 128;
#pragma unroll
        for (int c = 0; c < 4; c++) {
            int jc = sseg * 4 + c;
            uint4 v = *(const uint4*)(hrow + j0 + jc * 8);
            *(uint4*)(hstage + (sd * 16 + (jc ^ (sd & 15))) * 8) = v;
        }
        __syncthreads();

#pragma unroll
        for (int kk = 0; kk < 4; kk++) {
            const int jl = j0 + kk * 32 + q * 8;
            int4 a0 = *(const int4*)(mA + jl);
            int4 a1 = *(const int4*)(mA + jl + 4);
            int4 b0 = *(const int4*)(mJ + jl);
            int4 b1 = *(const int4*)(mJ + jl + 4);
            float4 d0 = *(const float4*)(adst + jl);
            float4 d1 = *(const float4*)(adst + jl + 4);
            int ma[8] = {a0.x, a0.y, a0.z, a0.w, a1.x, a1.y, a1.z, a1.w};
            int mj[8] = {b0.x, b0.y, b0.z, b0.w, b1.x, b1.y, b1.z, b1.w};
            float dv[8] = {d0.x, d0.y, d0.z, d0.w, d1.x, d1.y, d1.z, d1.w};
            bf16x8 fa, fj;
#pragma unroll
            for (int u = 0; u < 8; u++) {
                float e = asrc + dv[u];
                float le = fmaxf(e, 0.f) + 0.2f * fminf(e, 0.f);
                float p = __expf(le);            // no max-sub: e <= ~9
                float pa = (ma[u] == 1) ? p : 0.f;
                float pj = (mj[u] == 1) ? p : 0.f;
                zA += pa;
                zJ += pj;
                fa[u] = (short)f32_bf16_rne(pa);
                fj[u] = (short)f32_bf16_rne(pj);
            }
#pragma unroll
            for (int dd = 0; dd < 4; dd++) {
                int dn = dd * 16 + m;
                int jcl = kk * 4 + q;
                bf16x8 fb = *(const bf16x8*)(hstage + (dn * 16 + (jcl ^ (dn & 15))) * 8);
                accA[dd] = __builtin_amdgcn_mfma_f32_16x16x32_bf16(fa, fb, accA[dd], 0, 0, 0);
                accJ[dd] = __builtin_amdgcn_mfma_f32_16x16x32_bf16(fj, fb, accJ[dd], 0, 0, 0);
            }
        }
        __syncthreads();
    }

    // finish partial Z across q
    zA += __shfl_xor(zA, 16); zA += __shfl_xor(zA, 32);
    zJ += __shfl_xor(zJ, 16); zJ += __shfl_xor(zJ, 32);

    const size_t blk = (size_t)tile * S + blockIdx.y;
    float* pb = pacc + blk * 8192;               // [A: 64x64][J: 64x64]
    float* zr = zpart + blk * 128;
    if (q == 0) {
        zr[wid * 16 + m] = zA;
        zr[64 + wid * 16 + m] = zJ;
    }
#pragma unroll
    for (int dd = 0; dd < 4; dd++) {
        int d = dd * 16 + m;                     // C-frag col = lane&15
#pragma unroll
        for (int r = 0; r < 4; r++) {
            int i = wid * 16 + q * 4 + r;        // C-frag row = quad*4 + reg
            pb[i * 64 + d] = accA[dd][r];
            pb[4096 + i * 64 + d] = accJ[dd][r];
        }
    }
}

// Kernel C: sum S partials, normalize, lambda-blend, add residual.
// 256 blocks (one per row-tile) x 256 threads; thread t -> row t>>2, d-seg (t&3)*16.
__global__ __launch_bounds__(256) void combine_kernel(
    const float* __restrict__ pacc, const float* __restrict__ zpart,
    const float* __restrict__ feats, const float* __restrict__ lambda_params,
    float* __restrict__ out, int S) {
    const int tile = blockIdx.x;
    const int b = tile >> 5;
    const int rbase = (tile & 31) * 64;
    const int t = threadIdx.x;
    const int i = t >> 2;
    const int ds = (t & 3) * 16;

    const float* base = pacc + (size_t)tile * S * 8192;
    const float* zb = zpart + (size_t)tile * S * 128;

    float zA = 0.f, zJ = 0.f;
    float sA[16], sJ[16];
#pragma unroll
    for (int k = 0; k < 16; k++) { sA[k] = 0.f; sJ[k] = 0.f; }

    for (int s = 0; s < S; s++) {
        zA += zb[s * 128 + i];
        zJ += zb[s * 128 + 64 + i];
        const float* pA = base + (size_t)s * 8192 + i * 64 + ds;
        const float* pJ = pA + 4096;
#pragma unroll
        for (int k4 = 0; k4 < 4; k4++) {
            float4 vA = *(const float4*)(pA + k4 * 4);
            float4 vJ = *(const float4*)(pJ + k4 * 4);
            sA[k4 * 4 + 0] += vA.x; sA[k4 * 4 + 1] += vA.y;
            sA[k4 * 4 + 2] += vA.z; sA[k4 * 4 + 3] += vA.w;
            sJ[k4 * 4 + 0] += vJ.x; sJ[k4 * 4 + 1] += vJ.y;
            sJ[k4 * 4 + 2] += vJ.z; sJ[k4 * 4 + 3] += vJ.w;
        }
    }
    const float invA = 1.f / zA, invJ = 1.f / zJ;
    const size_t off = ((size_t)(b * N_ + rbase + i)) * D_ + ds;
#pragma unroll
    for (int k4 = 0; k4 < 4; k4++) {
        float4 f = *(const float4*)(feats + off + k4 * 4);
        float4 o;
        float* fo = (float*)&f;
        float* oo = (float*)&o;
#pragma unroll
        for (int c = 0; c < 4; c++) {
            int d = ds + k4 * 4 + c;
            float e0 = __expf(lambda_params[d * 2]);
            float e1 = __expf(lambda_params[d * 2 + 1]);
            float inv = 1.f / (e0 + e1);
            oo[c] = e0 * inv * sA[k4 * 4 + c] * invA +
                    e1 * inv * sJ[k4 * 4 + c] * invJ + fo[c];
        }
        *(float4*)(out + off + k4 * 4) = o;
    }
}

extern "C" void kernel_launch(void* const* d_in, const int* in_sizes, int n_in,
                              void* d_out, int out_size, void* d_ws, size_t ws_size,
                              hipStream_t stream) {
    const int* mask_adj = (const int*)d_in[0];
    const int* mask_job = (const int*)d_in[1];
    const int* batch_idxes = (const int*)d_in[2];
    const float* feats = (const float*)d_in[3];
    const float* W = (const float*)d_in[4];
    const float* attn_src = (const float*)d_in[5];
    const float* attn_dst = (const float*)d_in[6];
    const float* lambda_params = (const float*)d_in[7];
    float* out = (float*)d_out;

    // workspace layout
    unsigned short* hT = (unsigned short*)d_ws;                       // 2 MB
    char* p = (char*)d_ws + (size_t)B_ * 64 * N_ * 2;
    float* a_src = (float*)p;                                         // 64 KB
    float* a_dst = a_src + B_ * N_;                                   // 64 KB
    char* pz = p + 2 * (size_t)B_ * N_ * 4;

    // pick j-split S (per-slice fp32 partials): S=4 needs ~36 MB total ws
    auto need = [&](int S) {
        return (size_t)(pz - (char*)d_ws) +
               (size_t)256 * S * 128 * 4 +      // zpart
               (size_t)256 * S * 8192 * 4;      // pacc
    };
    int S = 4;
    if (ws_size < need(4)) S = 2;
    if (ws_size < need(2)) S = 1;

    float* zpart = (float*)pz;
    float* pacc = zpart + (size_t)256 * S * 128;

    prep_kernel<<<B_ * (N_ / 32), 256, 0, stream>>>(feats, W, attn_src, attn_dst,
                                                    hT, a_src, a_dst);
    dim3 grid(256, S, 1);
    attn_kernel<<<grid, 256, 0, stream>>>(mask_adj, mask_job, batch_idxes,
                                          hT, a_src, a_dst, pacc, zpart);
    combine_kernel<<<256, 256, 0, stream>>>(pacc, zpart, feats, lambda_params,
                                            out, S);
}